// Round 1
// baseline (479.366 us; speedup 1.0000x reference)
//
#include <hip/hip_runtime.h>
#include <math.h>

// PixPro fused masked all-pairs cosine loss, MI355X (gfx950).
// B=2048, C=256, H=W=7 -> P=49 pixels.
// out[b] = -(1/2401) * sum_{p,q} wt[p][q] * dot(base_p, mom_q)/max(nb_p*nm_q, eps)
// wt[p][q] = [base_A[p,q]==1] + [moment_A[q,p]==1].
//
// v3 structure:
//  - 2 waves per batch (channel split 128+128) -> 4096 waves = 4/SIMD occupancy.
//  - wave-private LDS slabs, NO block barriers in slab loop (lgkmcnt waits only)
//    -> register prefetch is truly async (no vmcnt(0) barrier drain).
//  - pixel-major slab layout [p][PITCH=12] (8 ch + 4 pad) -> aligned, bank-
//    conflict-free ds_read_b128 fragment reads (4 channels per instruction).
//  - mask weights staged as u8 (2.4 KB), partial acc/norms combined via LDS.

constexpr int NB     = 2048;
constexpr int NC     = 256;
constexpr int NP     = 49;            // 7*7 pixels
constexpr int SLAB_C = 8;             // channels per slab
constexpr int PITCH  = 12;            // words per pixel row (8 ch + 4 pad)
constexpr int FWORDS = NP * PITCH;    // 588 words per feature slab
constexpr int REGION = 1280;          // words per wave region (pair region 2560 >= 2529 exchange)
constexpr int NSLABW = (NC / 2) / SLAB_C;  // 8 slabs per wave
constexpr float EPS  = 1e-6f;

__global__ __launch_bounds__(256, 4)
void pixpro_kernel(const float* __restrict__ gbase,
                   const float* __restrict__ gmom,
                   const int*   __restrict__ A1,
                   const int*   __restrict__ A2,
                   float*       __restrict__ out)
{
    __shared__ unsigned char wtb[NP * NP];           // combined weights, u8 {0,1,2}
    __shared__ __align__(16) float slab[4][REGION];  // per-wave staging / exchange

    const int tid  = threadIdx.x;
    const int wave = tid >> 6;
    const int lane = tid & 63;
    const int b    = blockIdx.x * 2 + (wave >> 1);   // 2 batches per block
    const int half = wave & 1;                       // channel half [0,128) / [128,256)

    // --- stage combined mask weights as u8 (block-shared) ---
    for (int t = tid; t < NP * NP; t += 256) {
        int p = t / NP, q = t - p * NP;
        wtb[t] = (unsigned char)((A1[t] == 1 ? 1 : 0) + (A2[q * NP + p] == 1 ? 1 : 0));
    }
    __syncthreads();

    float* const sl  = slab[wave];
    float* const slb = sl;            // base slab  [p][PITCH]
    float* const slm = sl + FWORDS;   // mom  slab  [p][PITCH] (588*4=2352 B, 16-aligned)

    const int lp = lane & 7, lq = lane >> 3;
    const int p0 = (lp < 7 ? lp : 6) * 7;   // lanes lp==7/lq==7 duplicate tile 6, masked later
    const int q0 = (lq < 7 ? lq : 6) * 7;

    const float* gb = gbase + (size_t)b * (NC * NP) + (size_t)half * (128 * NP);
    const float* gm = gmom  + (size_t)b * (NC * NP) + (size_t)half * (128 * NP);

    // scatter word-offsets for slab staging (lane-invariant across slabs; hoisted)
    // element e in [0,392): c = e/49, p = e%49 -> W = p*PITCH + c
    int wof[8];
    #pragma unroll
    for (int u = 0; u < 4; ++u) {
        int e  = 4 * lane + u;
        wof[u] = (e - 49 * (e / 49)) * PITCH + (e / 49);
        int e2 = (lane < 34) ? (256 + 4 * lane + u) : 391;   // clamp: unused if lane>=34
        wof[4 + u] = (e2 - 49 * (e2 / 49)) * PITCH + (e2 / 49);
    }

    // norm-partial sources: lane<49 -> base pixel 'lane'; lane>=49 -> mom pixel lane-49.
    // second accumulator: lane<34 -> mom pixel 15+lane (clamped otherwise, unused).
    const float* const vA = (lane < NP) ? (slb + lane * PITCH)
                                        : (slm + (lane - NP) * PITCH);
    const float* const vB = slm + ((lane < 34) ? (15 + lane) : 48) * PITCH;
    const float* const bp = slb + p0 * PITCH;
    const float* const mp = slm + q0 * PITCH;

    float acc[7][7];
    #pragma unroll
    for (int j = 0; j < 7; ++j)
        #pragma unroll
        for (int i = 0; i < 7; ++i) acc[j][i] = 0.0f;
    float nrm0 = 0.0f, nrm1 = 0.0f;

    // --- prefetch slab 0 (98 float4 per feature) ---
    float4 rb0 = {}, rb1 = {}, rm0 = {}, rm1 = {};
    {
        const float4* pb = (const float4*)gb;
        const float4* pm = (const float4*)gm;
        rb0 = pb[lane]; rm0 = pm[lane];
        if (lane < 34) { rb1 = pb[64 + lane]; rm1 = pm[64 + lane]; }
    }

    for (int s = 0; s < NSLABW; ++s) {
        // scatter current slab into wave-private LDS (pixel-major, padded pitch)
        slb[wof[0]] = rb0.x; slb[wof[1]] = rb0.y; slb[wof[2]] = rb0.z; slb[wof[3]] = rb0.w;
        slm[wof[0]] = rm0.x; slm[wof[1]] = rm0.y; slm[wof[2]] = rm0.z; slm[wof[3]] = rm0.w;
        if (lane < 34) {
            slb[wof[4]] = rb1.x; slb[wof[5]] = rb1.y; slb[wof[6]] = rb1.z; slb[wof[7]] = rb1.w;
            slm[wof[4]] = rm1.x; slm[wof[5]] = rm1.y; slm[wof[6]] = rm1.z; slm[wof[7]] = rm1.w;
        }
        // prefetch next slab -- stays in flight across the whole compute phase
        // (no barrier below, so no vmcnt(0) drain)
        if (s + 1 < NSLABW) {
            const float4* pb = (const float4*)(gb + (s + 1) * (SLAB_C * NP));
            const float4* pm = (const float4*)(gm + (s + 1) * (SLAB_C * NP));
            rb0 = pb[lane]; rm0 = pm[lane];
            if (lane < 34) { rb1 = pb[64 + lane]; rm1 = pm[64 + lane]; }
        }
        // wave-local write->read visibility (slab is wave-private; no __syncthreads)
        asm volatile("s_waitcnt lgkmcnt(0)" ::: "memory");

        // compute: 2 chunks of 4 channels, all-b128 conflict-free LDS reads
        #pragma unroll
        for (int c0 = 0; c0 < SLAB_C; c0 += 4) {
            float4 mv[7];
            #pragma unroll
            for (int j = 0; j < 7; ++j)
                mv[j] = *(const float4*)(mp + j * PITCH + c0);
            float4 a4 = *(const float4*)(vA + c0);
            float4 b4 = *(const float4*)(vB + c0);
            nrm0 = fmaf(a4.x, a4.x, fmaf(a4.y, a4.y, fmaf(a4.z, a4.z, fmaf(a4.w, a4.w, nrm0))));
            nrm1 = fmaf(b4.x, b4.x, fmaf(b4.y, b4.y, fmaf(b4.z, b4.z, fmaf(b4.w, b4.w, nrm1))));
            #pragma unroll
            for (int i = 0; i < 7; ++i) {
                float4 bv = *(const float4*)(bp + i * PITCH + c0);
                #pragma unroll
                for (int j = 0; j < 7; ++j) {
                    float t0 = fmaf(bv.x, mv[j].x, acc[j][i]);
                    t0       = fmaf(bv.y, mv[j].y, t0);
                    t0       = fmaf(bv.z, mv[j].z, t0);
                    acc[j][i] = fmaf(bv.w, mv[j].w, t0);
                }
            }
        }
        // drain reads before next iteration's scatter writes (WAR safety)
        asm volatile("s_waitcnt lgkmcnt(0)" ::: "memory");
    }

    // --- combine the two channel-halves of each batch ---
    __syncthreads();   // all slab reads done; pair region reusable as exchange buffer

    float* const ex   = slab[wave & ~1];   // batch pair region: 2560 words
    const bool active = (lp < 7) && (lq < 7);
    const int  tix    = lq * 7 + lp;       // 0..48 for active lanes

    if (half) {  // odd wave publishes its partials
        ex[lane]      = nrm0;
        ex[64 + lane] = nrm1;
        if (active) {
            #pragma unroll
            for (int j = 0; j < 7; ++j)
                #pragma unroll
                for (int i = 0; i < 7; ++i)
                    ex[128 + tix * 49 + j * 7 + i] = acc[j][i];
        }
    }
    __syncthreads();

    if (!half) {  // even wave reduces and finishes
        nrm0 += ex[lane];
        nrm1 += ex[64 + lane];
        if (active) {
            #pragma unroll
            for (int j = 0; j < 7; ++j)
                #pragma unroll
                for (int i = 0; i < 7; ++i)
                    acc[j][i] += ex[128 + tix * 49 + j * 7 + i];
        }
        asm volatile("s_waitcnt lgkmcnt(0)" ::: "memory");

        // redistribute combined squared norms within the wave:
        // ex[0..48] = base pixel sums; ex[49..97] = mom pixel sums
        ex[lane] = nrm0;                       // lanes 0..48 base, 49..63 mom[0..14]
        if (lane < 34) ex[64 + lane] = nrm1;   // mom[15..48]
        asm volatile("s_waitcnt lgkmcnt(0)" ::: "memory");

        float nbv[7], nmv[7];
        #pragma unroll
        for (int i = 0; i < 7; ++i) nbv[i] = sqrtf(ex[p0 + i]);
        #pragma unroll
        for (int j = 0; j < 7; ++j) nmv[j] = sqrtf(ex[NP + q0 + j]);

        float sum = 0.0f;
        if (active) {
            #pragma unroll
            for (int j = 0; j < 7; ++j)
                #pragma unroll
                for (int i = 0; i < 7; ++i) {
                    float w     = (float)wtb[(p0 + i) * NP + (q0 + j)];
                    float denom = fmaxf(nbv[i] * nmv[j], EPS);
                    sum += w * acc[j][i] / denom;
                }
        }
        #pragma unroll
        for (int m = 32; m; m >>= 1) sum += __shfl_xor(sum, m, 64);
        if (lane == 0) out[b] = sum * (-1.0f / 2401.0f);
    }
}

extern "C" void kernel_launch(void* const* d_in, const int* in_sizes, int n_in,
                              void* d_out, int out_size, void* d_ws, size_t ws_size,
                              hipStream_t stream)
{
    (void)in_sizes; (void)n_in; (void)d_ws; (void)ws_size; (void)out_size;
    const float* base = (const float*)d_in[0];
    const float* mom  = (const float*)d_in[1];
    const int*   A1   = (const int*)d_in[2];
    const int*   A2   = (const int*)d_in[3];
    float*       out  = (float*)d_out;

    pixpro_kernel<<<NB / 2, 256, 0, stream>>>(base, mom, A1, A2, out);
}

// Round 2
// 262.460 us; speedup vs baseline: 1.8264x; 1.8264x over previous
//
#include <hip/hip_runtime.h>
#include <math.h>

// PixPro fused masked all-pairs cosine loss, MI355X (gfx950).
// B=2048, C=256, H=W=7 -> P=49 pixels.
// out[b] = -(1/2401) * sum_{p,q} wt[p][q] * dot(base_p, mom_q)/max(nb_p*nm_q, eps)
// wt[p][q] = [base_A[p,q]==1] + [moment_A[q,p]==1].
//
// v4 structure:
//  - 2 waves per batch (channel split 128+128) -> 4096 waves = 4/SIMD occupancy.
//  - __launch_bounds__(256,2): round-1's (256,4) forced VGPR=64 -> 542 MB scratch
//    spill traffic. Cap 256 lets allocator land ~128 (49 acc + fragments) with
//    zero spill; 128 VGPR still allows 4 waves/SIMD.
//  - wave-private LDS slabs, NO block barriers in slab loop (lgkmcnt waits only)
//    -> register prefetch stays in flight across the whole compute phase.
//  - pixel-major slab layout [p][PITCH=12] (8 ch + 4 pad) -> aligned, bank-
//    conflict-free ds_read_b128 fragment reads (4 channels per instruction).
//  - staging: lane l<49 loads float4 l and l+49; 196 words = 4 ch x 49 px, so
//    second load's scatter offsets are wof[u]+4 (half the offset registers).

constexpr int NB     = 2048;
constexpr int NC     = 256;
constexpr int NP     = 49;            // 7*7 pixels
constexpr int SLAB_C = 8;             // channels per slab (per wave-half)
constexpr int PITCH  = 12;            // words per pixel row (8 ch + 4 pad)
constexpr int FWORDS = NP * PITCH;    // 588 words per feature slab
constexpr int REGION = 1280;          // words per wave region (pair 2560 >= 2529 exchange)
constexpr int NSLABW = (NC / 2) / SLAB_C;  // 8 slabs per wave
constexpr float EPS  = 1e-6f;

__global__ __launch_bounds__(256, 2)
void pixpro_kernel(const float* __restrict__ gbase,
                   const float* __restrict__ gmom,
                   const int*   __restrict__ A1,
                   const int*   __restrict__ A2,
                   float*       __restrict__ out)
{
    __shared__ unsigned char wtb[NP * NP];           // combined weights, u8 {0,1,2}
    __shared__ __align__(16) float slab[4][REGION];  // per-wave staging / exchange

    const int tid  = threadIdx.x;
    const int wave = tid >> 6;
    const int lane = tid & 63;
    const int b    = blockIdx.x * 2 + (wave >> 1);   // 2 batches per block
    const int half = wave & 1;                       // channel half [0,128) / [128,256)

    // --- stage combined mask weights as u8 (block-shared) ---
    for (int t = tid; t < NP * NP; t += 256) {
        int p = t / NP, q = t - p * NP;
        wtb[t] = (unsigned char)((A1[t] == 1 ? 1 : 0) + (A2[q * NP + p] == 1 ? 1 : 0));
    }
    __syncthreads();

    float* const sl  = slab[wave];
    float* const slb = sl;            // base slab  [p][PITCH]
    float* const slm = sl + FWORDS;   // mom  slab  [p][PITCH] (588*4=2352 B, 16-aligned)

    const int lp = lane & 7, lq = lane >> 3;
    const int p0 = (lp < 7 ? lp : 6) * 7;   // lanes lp==7/lq==7 duplicate tile 6, masked later
    const int q0 = (lq < 7 ? lq : 6) * 7;

    const float* gb = gbase + (size_t)b * (NC * NP) + (size_t)half * (128 * NP);
    const float* gm = gmom  + (size_t)b * (NC * NP) + (size_t)half * (128 * NP);

    const bool ld = (lane < NP);   // staging lanes: l<49 load float4 l and l+49

    // scatter word-offsets: element e = 4*lane+u -> (c=e/49, p=e%49) -> p*PITCH+c.
    // second float4 (index lane+49) is e+196 = +4 channels -> offset wof[u]+4.
    int wof[4];
    #pragma unroll
    for (int u = 0; u < 4; ++u) {
        int e  = 4 * lane + u;
        wof[u] = (e - 49 * (e / 49)) * PITCH + (e / 49);
    }

    // norm-partial sources: lane<49 -> base pixel 'lane'; lane>=49 -> mom pixel lane-49.
    // second accumulator: lane<34 -> mom pixel 15+lane (clamped otherwise, unused).
    const float* const vA = (lane < NP) ? (slb + lane * PITCH)
                                        : (slm + (lane - NP) * PITCH);
    const float* const vB = slm + ((lane < 34) ? (15 + lane) : 48) * PITCH;
    const float* const bp = slb + p0 * PITCH;
    const float* const mp = slm + q0 * PITCH;

    float acc[7][7];
    #pragma unroll
    for (int j = 0; j < 7; ++j)
        #pragma unroll
        for (int i = 0; i < 7; ++i) acc[j][i] = 0.0f;
    float nrm0 = 0.0f, nrm1 = 0.0f;

    // --- prefetch slab 0 (98 float4 per feature; lanes 0..48 take two each) ---
    float4 rb0 = {}, rb1 = {}, rm0 = {}, rm1 = {};
    if (ld) {
        const float4* pb = (const float4*)gb;
        const float4* pm = (const float4*)gm;
        rb0 = pb[lane]; rb1 = pb[lane + NP];
        rm0 = pm[lane]; rm1 = pm[lane + NP];
    }

    for (int s = 0; s < NSLABW; ++s) {
        // scatter current slab into wave-private LDS (pixel-major, padded pitch)
        if (ld) {
            slb[wof[0]]     = rb0.x; slb[wof[1]]     = rb0.y; slb[wof[2]]     = rb0.z; slb[wof[3]]     = rb0.w;
            slb[wof[0] + 4] = rb1.x; slb[wof[1] + 4] = rb1.y; slb[wof[2] + 4] = rb1.z; slb[wof[3] + 4] = rb1.w;
            slm[wof[0]]     = rm0.x; slm[wof[1]]     = rm0.y; slm[wof[2]]     = rm0.z; slm[wof[3]]     = rm0.w;
            slm[wof[0] + 4] = rm1.x; slm[wof[1] + 4] = rm1.y; slm[wof[2] + 4] = rm1.z; slm[wof[3] + 4] = rm1.w;
        }
        // prefetch next slab -- stays in flight across the whole compute phase
        // (no barrier below, so no vmcnt(0) drain)
        if (s + 1 < NSLABW && ld) {
            const float4* pb = (const float4*)(gb + (s + 1) * (SLAB_C * NP));
            const float4* pm = (const float4*)(gm + (s + 1) * (SLAB_C * NP));
            rb0 = pb[lane]; rb1 = pb[lane + NP];
            rm0 = pm[lane]; rm1 = pm[lane + NP];
        }
        // wave-local write->read visibility (slab is wave-private; no __syncthreads)
        asm volatile("s_waitcnt lgkmcnt(0)" ::: "memory");

        // compute: 2 chunks of 4 channels, all-b128 conflict-free LDS reads
        #pragma unroll
        for (int c0 = 0; c0 < SLAB_C; c0 += 4) {
            float4 mv[7];
            #pragma unroll
            for (int j = 0; j < 7; ++j)
                mv[j] = *(const float4*)(mp + j * PITCH + c0);
            float4 a4 = *(const float4*)(vA + c0);
            float4 b4 = *(const float4*)(vB + c0);
            nrm0 = fmaf(a4.x, a4.x, fmaf(a4.y, a4.y, fmaf(a4.z, a4.z, fmaf(a4.w, a4.w, nrm0))));
            nrm1 = fmaf(b4.x, b4.x, fmaf(b4.y, b4.y, fmaf(b4.z, b4.z, fmaf(b4.w, b4.w, nrm1))));
            #pragma unroll
            for (int i = 0; i < 7; ++i) {
                float4 bv = *(const float4*)(bp + i * PITCH + c0);
                #pragma unroll
                for (int j = 0; j < 7; ++j) {
                    float t0 = fmaf(bv.x, mv[j].x, acc[j][i]);
                    t0       = fmaf(bv.y, mv[j].y, t0);
                    t0       = fmaf(bv.z, mv[j].z, t0);
                    acc[j][i] = fmaf(bv.w, mv[j].w, t0);
                }
            }
        }
        // drain reads before next iteration's scatter writes (WAR safety)
        asm volatile("s_waitcnt lgkmcnt(0)" ::: "memory");
    }

    // --- combine the two channel-halves of each batch ---
    __syncthreads();   // all slab reads done; pair region reusable as exchange buffer

    float* const ex   = slab[wave & ~1];   // batch pair region: 2560 words
    const bool active = (lp < 7) && (lq < 7);
    const int  tix    = lq * 7 + lp;       // 0..48 for active lanes

    if (half) {  // odd wave publishes its partials
        ex[lane]      = nrm0;
        ex[64 + lane] = nrm1;
        if (active) {
            #pragma unroll
            for (int j = 0; j < 7; ++j)
                #pragma unroll
                for (int i = 0; i < 7; ++i)
                    ex[128 + tix * 49 + j * 7 + i] = acc[j][i];
        }
    }
    __syncthreads();

    if (!half) {  // even wave reduces and finishes
        nrm0 += ex[lane];
        nrm1 += ex[64 + lane];
        if (active) {
            #pragma unroll
            for (int j = 0; j < 7; ++j)
                #pragma unroll
                for (int i = 0; i < 7; ++i)
                    acc[j][i] += ex[128 + tix * 49 + j * 7 + i];
        }
        asm volatile("s_waitcnt lgkmcnt(0)" ::: "memory");

        // redistribute combined squared norms within the wave:
        // ex[0..48] = base pixel sums; ex[49..97] = mom pixel sums
        ex[lane] = nrm0;                       // lanes 0..48 base, 49..63 mom[0..14]
        if (lane < 34) ex[64 + lane] = nrm1;   // mom[15..48]
        asm volatile("s_waitcnt lgkmcnt(0)" ::: "memory");

        float nbv[7], nmv[7];
        #pragma unroll
        for (int i = 0; i < 7; ++i) nbv[i] = sqrtf(ex[p0 + i]);
        #pragma unroll
        for (int j = 0; j < 7; ++j) nmv[j] = sqrtf(ex[NP + q0 + j]);

        float sum = 0.0f;
        if (active) {
            #pragma unroll
            for (int j = 0; j < 7; ++j)
                #pragma unroll
                for (int i = 0; i < 7; ++i) {
                    float w     = (float)wtb[(p0 + i) * NP + (q0 + j)];
                    float denom = fmaxf(nbv[i] * nmv[j], EPS);
                    sum += w * acc[j][i] / denom;
                }
        }
        #pragma unroll
        for (int m = 32; m; m >>= 1) sum += __shfl_xor(sum, m, 64);
        if (lane == 0) out[b] = sum * (-1.0f / 2401.0f);
    }
}

extern "C" void kernel_launch(void* const* d_in, const int* in_sizes, int n_in,
                              void* d_out, int out_size, void* d_ws, size_t ws_size,
                              hipStream_t stream)
{
    (void)in_sizes; (void)n_in; (void)d_ws; (void)ws_size; (void)out_size;
    const float* base = (const float*)d_in[0];
    const float* mom  = (const float*)d_in[1];
    const int*   A1   = (const int*)d_in[2];
    const int*   A2   = (const int*)d_in[3];
    float*       out  = (float*)d_out;

    pixpro_kernel<<<NB / 2, 256, 0, stream>>>(base, mom, A1, A2, out);
}

// Round 3
// 248.441 us; speedup vs baseline: 1.9295x; 1.0564x over previous
//
#include <hip/hip_runtime.h>
#include <math.h>

// PixPro fused masked all-pairs cosine loss, MI355X (gfx950).
// B=2048, C=256, H=W=7 -> P=49 pixels.
// out[b] = -(1/2401) * sum_{p,q} wt[p][q] * dot(base_p, mom_q)/max(nb_p*nm_q, eps)
// wt[p][q] = [base_A[p,q]==1] + [moment_A[q,p]==1].
//
// v5 structure:
//  - 2 waves per batch (channel split 128+128), 1024 blocks -> 4096 waves.
//  - TRANSPOSED GLOBAL LOADS: lane l<49 owns pixel l; 4 scalar loads at
//    stride 49 words gather channels 4s..4s+3 of that pixel (each instr is a
//    contiguous 196B segment across lanes -> coalesced). One ds_write_b128 at
//    word 4*l per feature: quad banks cycle all 8 positions -> conflict-free.
//    (v4's pixel-major scatter from pixel-consecutive float4s put all lanes on
//    2 banks -> 25-way conflict, 11.5M conflict cycles. Structural; fixed here.)
//  - dense [p][4ch] layout, PITCH=4: fragment reads are b128 with lp/lq groups
//    on disjoint bank quads; norm reads fully spread. All 16B aligned.
//  - SLAB_C=4, 32 slabs, double-buffered LDS, depth-2 register prefetch
//    (2 reg sets ping-pong; ds_write frees a set before its reload).
//  - VGPR target <=120: m69 boundary suggests 128 VGPR caps at 2 waves/SIMD
//    (round-2: occupancy 19.5% at VGPR=128 vs 44.9% at 64). <=120 -> 4/SIMD.

constexpr int NB     = 2048;
constexpr int NC     = 256;
constexpr int NP     = 49;            // 7*7 pixels
constexpr int SLAB_C = 4;             // channels per slab
constexpr int FW     = NP * SLAB_C;   // 196 words per feature per slab
constexpr int BUFW   = 2 * FW;        // 392 words per slab buffer (base|mom)
constexpr int REGION = 1280;          // words per wave region (pair 2560 >= 2529 exchange)
constexpr int NSLABW = (NC / 2) / SLAB_C;  // 32 slabs per wave
constexpr float EPS  = 1e-6f;

__global__ __launch_bounds__(256, 2)
void pixpro_kernel(const float* __restrict__ gbase,
                   const float* __restrict__ gmom,
                   const int*   __restrict__ A1,
                   const int*   __restrict__ A2,
                   float*       __restrict__ out)
{
    __shared__ unsigned char wtb[NP * NP];           // combined weights, u8 {0,1,2}
    __shared__ __align__(16) float slab[4][REGION];  // per-wave staging / exchange

    const int tid  = threadIdx.x;
    const int wave = tid >> 6;
    const int lane = tid & 63;
    const int b    = blockIdx.x * 2 + (wave >> 1);   // 2 batches per block
    const int half = wave & 1;                       // channel half [0,128) / [128,256)

    // --- stage combined mask weights as u8 (block-shared) ---
    for (int t = tid; t < NP * NP; t += 256) {
        int p = t / NP, q = t - p * NP;
        wtb[t] = (unsigned char)((A1[t] == 1 ? 1 : 0) + (A2[q * NP + p] == 1 ? 1 : 0));
    }
    __syncthreads();

    float* const sl = slab[wave];

    const int lp = lane & 7, lq = lane >> 3;
    const int p0 = (lp < 7 ? lp : 6) * 7;   // lanes lp==7/lq==7 duplicate tile 6, masked later
    const int q0 = (lq < 7 ? lq : 6) * 7;

    const float* gb = gbase + (size_t)b * (NC * NP) + (size_t)half * (128 * NP);
    const float* gm = gmom  + (size_t)b * (NC * NP) + (size_t)half * (128 * NP);
    const float* gbl = gb + lane;   // per-lane: pixel 'lane' of channel c at gbl[c*NP]
    const float* gml = gm + lane;

    const bool ld = (lane < NP);

    // per-lane LDS word offsets (buffer-relative; buffer select via +Boff const)
    // norm sources: lane<49 -> base pixel lane; lane>=49 -> mom pixel lane-49;
    // second: lane<34 -> mom pixel 15+lane (clamped otherwise, unused).
    const int vAw = (lane < NP) ? (4 * lane) : (FW + 4 * (lane - NP));
    const int vBw = FW + 4 * ((lane < 34) ? (15 + lane) : 48);

    float acc[7][7];
    #pragma unroll
    for (int j = 0; j < 7; ++j)
        #pragma unroll
        for (int i = 0; i < 7; ++i) acc[j][i] = 0.0f;
    float nrm0 = 0.0f, nrm1 = 0.0f;

    // depth-2 register prefetch, two sets (A,B) ping-ponged
    float4 pbA = {}, pmA = {}, pbB = {}, pmB = {};
    if (ld) {
        pbA.x = gbl[0];      pbA.y = gbl[NP];      pbA.z = gbl[2 * NP];      pbA.w = gbl[3 * NP];
        pmA.x = gml[0];      pmA.y = gml[NP];      pmA.z = gml[2 * NP];      pmA.w = gml[3 * NP];
        pbB.x = gbl[FW];     pbB.y = gbl[FW + NP]; pbB.z = gbl[FW + 2 * NP]; pbB.w = gbl[FW + 3 * NP];
        pmB.x = gml[FW];     pmB.y = gml[FW + NP]; pmB.z = gml[FW + 2 * NP]; pmB.w = gml[FW + 3 * NP];
    }

    auto compute = [&](int Boff) {
        const float* base_ = sl + Boff;
        float4 a4 = *(const float4*)(base_ + vAw);
        float4 b4 = *(const float4*)(base_ + vBw);
        nrm0 = fmaf(a4.x, a4.x, fmaf(a4.y, a4.y, fmaf(a4.z, a4.z, fmaf(a4.w, a4.w, nrm0))));
        nrm1 = fmaf(b4.x, b4.x, fmaf(b4.y, b4.y, fmaf(b4.z, b4.z, fmaf(b4.w, b4.w, nrm1))));
        float4 mv[7];
        #pragma unroll
        for (int j = 0; j < 7; ++j)
            mv[j] = *(const float4*)(base_ + FW + q0 * 4 + 4 * j);
        #pragma unroll
        for (int i = 0; i < 7; ++i) {
            float4 bv = *(const float4*)(base_ + p0 * 4 + 4 * i);
            #pragma unroll
            for (int j = 0; j < 7; ++j) {
                float t0 = fmaf(bv.x, mv[j].x, acc[j][i]);
                t0       = fmaf(bv.y, mv[j].y, t0);
                t0       = fmaf(bv.z, mv[j].z, t0);
                acc[j][i] = fmaf(bv.w, mv[j].w, t0);
            }
        }
    };

    for (int s = 0; s < NSLABW; s += 2) {
        // ---- even slab: buffer 0, reg set A ----
        if (ld) {
            *(float4*)(sl + 4 * lane)      = pbA;
            *(float4*)(sl + FW + 4 * lane) = pmA;
            if (s + 2 < NSLABW) {           // reload set A for slab s+2
                const float* pb_ = gbl + (s + 2) * FW;
                const float* pm_ = gml + (s + 2) * FW;
                pbA.x = pb_[0]; pbA.y = pb_[NP]; pbA.z = pb_[2 * NP]; pbA.w = pb_[3 * NP];
                pmA.x = pm_[0]; pmA.y = pm_[NP]; pmA.z = pm_[2 * NP]; pmA.w = pm_[3 * NP];
            }
        }
        asm volatile("s_waitcnt lgkmcnt(0)" ::: "memory");
        compute(0);

        // ---- odd slab: buffer BUFW, reg set B ----
        if (ld) {
            *(float4*)(sl + BUFW + 4 * lane)      = pbB;
            *(float4*)(sl + BUFW + FW + 4 * lane) = pmB;
            if (s + 3 < NSLABW) {           // reload set B for slab s+3
                const float* pb_ = gbl + (s + 3) * FW;
                const float* pm_ = gml + (s + 3) * FW;
                pbB.x = pb_[0]; pbB.y = pb_[NP]; pbB.z = pb_[2 * NP]; pbB.w = pb_[3 * NP];
                pmB.x = pm_[0]; pmB.y = pm_[NP]; pmB.z = pm_[2 * NP]; pmB.w = pm_[3 * NP];
            }
        }
        asm volatile("s_waitcnt lgkmcnt(0)" ::: "memory");
        compute(BUFW);
    }

    // --- combine the two channel-halves of each batch ---
    __syncthreads();   // all slab reads done; pair region reusable as exchange buffer

    float* const ex   = slab[wave & ~1];   // batch pair region: 2560 words
    const bool active = (lp < 7) && (lq < 7);
    const int  tix    = lq * 7 + lp;       // 0..48 for active lanes

    if (half) {  // odd wave publishes its partials
        ex[lane]      = nrm0;
        ex[64 + lane] = nrm1;
        if (active) {
            #pragma unroll
            for (int j = 0; j < 7; ++j)
                #pragma unroll
                for (int i = 0; i < 7; ++i)
                    ex[128 + tix * 49 + j * 7 + i] = acc[j][i];
        }
    }
    __syncthreads();

    if (!half) {  // even wave reduces and finishes
        nrm0 += ex[lane];
        nrm1 += ex[64 + lane];
        if (active) {
            #pragma unroll
            for (int j = 0; j < 7; ++j)
                #pragma unroll
                for (int i = 0; i < 7; ++i)
                    acc[j][i] += ex[128 + tix * 49 + j * 7 + i];
        }
        asm volatile("s_waitcnt lgkmcnt(0)" ::: "memory");

        // redistribute combined squared norms within the wave:
        // ex[0..48] = base pixel sums; ex[49..97] = mom pixel sums
        ex[lane] = nrm0;                       // lanes 0..48 base, 49..63 mom[0..14]
        if (lane < 34) ex[64 + lane] = nrm1;   // mom[15..48]
        asm volatile("s_waitcnt lgkmcnt(0)" ::: "memory");

        float nbv[7], nmv[7];
        #pragma unroll
        for (int i = 0; i < 7; ++i) nbv[i] = sqrtf(ex[p0 + i]);
        #pragma unroll
        for (int j = 0; j < 7; ++j) nmv[j] = sqrtf(ex[NP + q0 + j]);

        float sum = 0.0f;
        if (active) {
            #pragma unroll
            for (int j = 0; j < 7; ++j)
                #pragma unroll
                for (int i = 0; i < 7; ++i) {
                    float w     = (float)wtb[(p0 + i) * NP + (q0 + j)];
                    float denom = fmaxf(nbv[i] * nmv[j], EPS);
                    sum += w * acc[j][i] / denom;
                }
        }
        #pragma unroll
        for (int m = 32; m; m >>= 1) sum += __shfl_xor(sum, m, 64);
        if (lane == 0) out[b] = sum * (-1.0f / 2401.0f);
    }
}

extern "C" void kernel_launch(void* const* d_in, const int* in_sizes, int n_in,
                              void* d_out, int out_size, void* d_ws, size_t ws_size,
                              hipStream_t stream)
{
    (void)in_sizes; (void)n_in; (void)d_ws; (void)ws_size; (void)out_size;
    const float* base = (const float*)d_in[0];
    const float* mom  = (const float*)d_in[1];
    const int*   A1   = (const int*)d_in[2];
    const int*   A2   = (const int*)d_in[3];
    float*       out  = (float*)d_out;

    pixpro_kernel<<<NB / 2, 256, 0, stream>>>(base, mom, A1, A2, out);
}